// Round 8
// baseline (1762.297 us; speedup 1.0000x reference)
//
#include <hip/hip_runtime.h>
#include <hip/hip_bf16.h>

#define T_STEPS 64
#define B_DIM 2048
#define U_DIM 1024

#define BM 256          // batch rows per block
#define BU 32           // u-cols per block (f & c halves)
#define BK 32
#define KITERS (U_DIM / BK)   // 32
#define BSTR 1032             // padded B row stride (halfs): conflict-free b128

typedef __attribute__((ext_vector_type(8))) _Float16 h8;
typedef __attribute__((ext_vector_type(4))) float f4;

__device__ __forceinline__ void async_cp16(const _Float16* g, _Float16* l) {
    __builtin_amdgcn_global_load_lds((const __attribute__((address_space(1))) void*)g,
                                     (__attribute__((address_space(3))) void*)l,
                                     16, 0, 0);
}

// ---------------- init kernels ----------------

// R: [U][2U] f32 row-major -> Rt: [2U][U] f16 (B^T layout)
__global__ void transpose_R(const float* __restrict__ R, _Float16* __restrict__ Rt) {
    __shared__ float tile[32][33];
    int nb = blockIdx.x * 32;
    int kb = blockIdx.y * 32;
    int tx = threadIdx.x, ty = threadIdx.y;   // block (32,8)
    #pragma unroll
    for (int i = ty; i < 32; i += 8)
        tile[i][tx] = R[(size_t)(kb + i) * (2 * U_DIM) + nb + tx];
    __syncthreads();
    #pragma unroll
    for (int i = ty; i < 32; i += 8)
        Rt[(size_t)(nb + i) * U_DIM + kb + tx] = (_Float16)tile[tx][i];
}

__global__ void init_state(const float* __restrict__ c0, _Float16* __restrict__ h0,
                           float* __restrict__ y) {
    int i = blockIdx.x * 256 + threadIdx.x;
    h0[i] = (_Float16)c0[i];
    if (i < 3 * B_DIM) y[i] = 0.f;
}

// ---------------- per-step fused kernel ----------------
// Barrier-free K-loop: B (Rf/Rc u-slice) persistent in LDS, A direct to VGPR.
__global__ __launch_bounds__(256, 1) void gemm_step(
    const _Float16* __restrict__ hA, _Float16* __restrict__ hB,
    const _Float16* __restrict__ Rt,
    const float* __restrict__ x1_0, const float* __restrict__ x2_0,
    float* __restrict__ x1w,          // [2][B]
    float* __restrict__ x2w,          // [2][B]
    const float* __restrict__ kern, const float* __restrict__ bias,
    const float* __restrict__ okern,
    float* __restrict__ y,            // [3][B]
    const float* __restrict__ inputs, // [T][B]
    float* __restrict__ out,          // [T][B]
    int t)
{
    __shared__ __align__(16) _Float16 lB[2][BU * BSTR];   // 129 KB
    __shared__ __align__(16) _Float16 lH[BM * BU];        // 16 KB (h tile, then c tile)
    __shared__ float x1s[BM];                             // 1 KB

    const int tid    = threadIdx.x;
    const int wid    = tid >> 6;
    const int lane   = tid & 63;
    const int lane15 = lane & 15;
    const int quad   = lane >> 4;
    const int ublk   = blockIdx.x;
    const int u0     = ublk * BU;
    const int b0     = blockIdx.y * BM;
    const int wrow   = wid * 64;

    // ---- load persistent B tiles (coalesced global, sequential LDS writes) ----
    #pragma unroll 8
    for (int i = 0; i < 32; ++i) {
        const int idx = i * 256 + tid;          // 0..8191
        const int c   = idx & 127;
        const int r   = (idx >> 7) & 31;
        const int hf  = idx >> 12;
        const h8 v = *(const h8*)&Rt[(size_t)(hf * U_DIM + u0 + r) * U_DIM + c * 8];
        *(h8*)&lB[hf][r * BSTR + c * 8] = v;
    }

    // ---- prologue: integrator state for this step ----
    {
        const int b = b0 + tid;
        float x1n, x2n;
        if (t == 0) {
            x1n = x1_0[b];
            x2n = x2_0[b];
        } else {
            const int rd = (t + 1) & 1;
            const float x1p = x1w[rd * B_DIM + b];
            const float x2p = x2w[rd * B_DIM + b];
            const float yp  = y[((t + 2) % 3) * B_DIM + b];
            const float ip  = inputs[(size_t)(t - 1) * B_DIM + b];
            x1n = x1p + x2p;
            x2n = x2p + ip * yp;
        }
        x1s[tid] = x1n;
        if (ublk == 0) {
            const int wr = t & 1;
            x1w[wr * B_DIM + b] = x1n;
            x2w[wr * B_DIM + b] = x2n;
            if (t > 0) out[(size_t)(t - 1) * B_DIM + b] = x1n;
            y[((t + 1) % 3) * B_DIM + b] = 0.f;
        }
    }

    // ---- epilogue constants into registers ----
    float kf[2], kc[2], bf_[2], bc_[2], ok_[2];
    #pragma unroll
    for (int nt = 0; nt < 2; ++nt) {
        const int u = u0 + nt * 16 + lane15;
        kf[nt] = kern[u];
        kc[nt] = kern[U_DIM + u];
        bf_[nt] = bias[u];
        bc_[nt] = bias[U_DIM + u];
        ok_[nt] = okern[u];
    }

    // ---- h-tile DMA (rows b0..b0+255, cols u0..u0+31) into lH, async ----
    #pragma unroll
    for (int j = 0; j < 4; ++j) {
        const int r = wid * 4 + j;    // 16 regions of 1 KB (16 rows x 64B)
        const _Float16* g = hA + (size_t)(b0 + r * 16 + (lane >> 2)) * U_DIM
                               + u0 + (lane & 3) * 8;
        async_cp16(g, &lH[r * 512]);
    }

    __syncthreads();   // lB + x1s ready (lH waited later)

    // ---- barrier-free K-loop: A register dbuf, B from LDS ----
    f4 accF[4][2], accC[4][2];
    #pragma unroll
    for (int mt = 0; mt < 4; ++mt)
        #pragma unroll
        for (int nt = 0; nt < 2; ++nt) {
            accF[mt][nt] = (f4){0.f, 0.f, 0.f, 0.f};
            accC[mt][nt] = (f4){0.f, 0.f, 0.f, 0.f};
        }

    h8 a[2][4];
    #pragma unroll
    for (int mt = 0; mt < 4; ++mt)
        a[0][mt] = *(const h8*)&hA[(size_t)(b0 + wrow + mt * 16 + lane15) * U_DIM + quad * 8];

    #pragma unroll 2
    for (int kt = 0; kt < KITERS; ++kt) {
        if (kt + 1 < KITERS) {
            const size_t k0 = (size_t)(kt + 1) * BK + quad * 8;
            #pragma unroll
            for (int mt = 0; mt < 4; ++mt)
                a[(kt + 1) & 1][mt] =
                    *(const h8*)&hA[(size_t)(b0 + wrow + mt * 16 + lane15) * U_DIM + k0];
        }
        h8 bff[2], bcc[2];
        #pragma unroll
        for (int nt = 0; nt < 2; ++nt) {
            const int off = (nt * 16 + lane15) * BSTR + kt * BK + quad * 8;
            bff[nt] = *(const h8*)&lB[0][off];
            bcc[nt] = *(const h8*)&lB[1][off];
        }
        #pragma unroll
        for (int mt = 0; mt < 4; ++mt)
            #pragma unroll
            for (int nt = 0; nt < 2; ++nt) {
                accF[mt][nt] = __builtin_amdgcn_mfma_f32_16x16x32_f16(a[kt & 1][mt], bff[nt], accF[mt][nt], 0, 0, 0);
                accC[mt][nt] = __builtin_amdgcn_mfma_f32_16x16x32_f16(a[kt & 1][mt], bcc[nt], accC[mt][nt], 0, 0, 0);
            }
    }

    __builtin_amdgcn_s_waitcnt(0x0F70);   // vmcnt(0): lH DMA complete
    __syncthreads();

    // ---- epilogue: gates; c in-place over lH; y partials ----
    float* ycur = y + (t % 3) * B_DIM;
    #pragma unroll
    for (int mt = 0; mt < 4; ++mt) {
        const int rlb = wrow + mt * 16 + quad * 4;
        float psum[4] = {0.f, 0.f, 0.f, 0.f};
        #pragma unroll
        for (int nt = 0; nt < 2; ++nt) {
            const int ul = nt * 16 + lane15;
            #pragma unroll
            for (int reg = 0; reg < 4; ++reg) {
                const int rl = rlb + reg;
                const float x1 = x1s[rl];
                const float xf = accF[mt][nt][reg] + x1 * kf[nt] + bf_[nt];
                const float xc = accC[mt][nt][reg] + x1 * kc[nt] + bc_[nt];
                const float fg = 1.f / (1.f + __expf(-xf));
                const float th = 1.f - 2.f / (1.f + __expf(2.f * xc));
                const float hv = (float)lH[rl * BU + ul];
                const float cv = fg * hv + (1.f - fg) * th;
                lH[rl * BU + ul] = (_Float16)cv;   // same-thread slot: no hazard
                psum[reg] += cv * ok_[nt];
            }
        }
        #pragma unroll
        for (int reg = 0; reg < 4; ++reg) {
            float s = psum[reg];
            s += __shfl_xor(s, 1);
            s += __shfl_xor(s, 2);
            s += __shfl_xor(s, 4);
            s += __shfl_xor(s, 8);
            if (lane15 == 0) atomicAdd(&ycur[b0 + rlb + reg], s);
        }
    }

    // ---- coalesced c write-out ----
    __syncthreads();
    #pragma unroll
    for (int j = 0; j < 4; ++j) {
        const int idx = j * 256 + tid;    // 1024 chunks = 256 rows x 4
        const int row = idx >> 2;
        const int c4  = idx & 3;
        *(uint4*)&hB[(size_t)(b0 + row) * U_DIM + u0 + c4 * 8] =
            *(const uint4*)&lH[row * BU + c4 * 8];
    }
}

// ---------------- tail: out[T-1] = x1(T) ----------------
__global__ void finish(const float* __restrict__ x1w1, const float* __restrict__ x2w1,
                       float* __restrict__ out_last) {
    const int i = blockIdx.x * 256 + threadIdx.x;
    out_last[i] = x1w1[i] + x2w1[i];
}

// ---------------- host ----------------
extern "C" void kernel_launch(void* const* d_in, const int* in_sizes, int n_in,
                              void* d_out, int out_size, void* d_ws, size_t ws_size,
                              hipStream_t stream) {
    const float* inputs = (const float*)d_in[0];
    const float* x1_0   = (const float*)d_in[1];
    const float* x2_0   = (const float*)d_in[2];
    const float* c0     = (const float*)d_in[3];
    const float* kern   = (const float*)d_in[4];
    const float* rker   = (const float*)d_in[5];
    const float* bias   = (const float*)d_in[6];
    const float* okern  = (const float*)d_in[7];
    float* out = (float*)d_out;

    _Float16* Rt = (_Float16*)d_ws;                       // 4 MB
    _Float16* h0 = Rt + (size_t)2 * U_DIM * U_DIM;        // 4 MB
    _Float16* h1 = h0 + (size_t)B_DIM * U_DIM;            // 4 MB
    float* y   = (float*)(h1 + (size_t)B_DIM * U_DIM);    // 3*B
    float* x1w = y + 3 * B_DIM;                           // 2*B
    float* x2w = x1w + 2 * B_DIM;                         // 2*B

    transpose_R<<<dim3(64, 32), dim3(32, 8), 0, stream>>>(rker, Rt);
    init_state<<<dim3(B_DIM * U_DIM / 256), dim3(256), 0, stream>>>(c0, h0, y);

    _Float16* hcur = h0;
    _Float16* hnxt = h1;
    for (int t = 0; t < T_STEPS; ++t) {
        gemm_step<<<dim3(U_DIM / BU, B_DIM / BM), dim3(256), 0, stream>>>(
            hcur, hnxt, Rt, x1_0, x2_0, x1w, x2w, kern, bias, okern, y,
            inputs, out, t);
        _Float16* tmp = hcur; hcur = hnxt; hnxt = tmp;
    }
    finish<<<dim3(B_DIM / 256), dim3(256), 0, stream>>>(
        x1w + B_DIM, x2w + B_DIM, out + (size_t)(T_STEPS - 1) * B_DIM);
}